// Round 1
// baseline (527.883 us; speedup 1.0000x reference)
//
#include <hip/hip_runtime.h>
#include <hip/hip_bf16.h>
#include <math.h>

// Problem constants (b=4,h=8,t=8192,d=64, c=64 clusters, wsz=128)
#define NB 4
#define NH 8
#define TT 8192
#define DD 64
#define NC 64
#define WW 128
#define BHN 32            // NB*NH
#define SCALE 0.125f      // d^-0.5

typedef __bf16 bf16x8 __attribute__((ext_vector_type(8)));
typedef float  f32x4  __attribute__((ext_vector_type(4)));

#define MFMA(a, b, c) __builtin_amdgcn_mfma_f32_16x16x32_bf16((a), (b), (c), 0, 0, 0)

// ---------------------------------------------------------------------------
// Kernel 1: routing dists in fp64 (+ commitment-loss partial sums)
// dists[bh][c][t] = (qk[bh][t] . means[h][c]) / max(||qk[bh][t]||, 1e-12)
// loss term per token: ||k||^2 + ||m_best||^2 - 2*dmax
// ---------------------------------------------------------------------------
__global__ __launch_bounds__(256) void k_dists(
    const float* __restrict__ qk, const float* __restrict__ means,
    double* __restrict__ dists, double* __restrict__ lossa)
{
    __shared__ float  mS[NC * DD];     // 16 KB
    __shared__ double mn2[NC];
    __shared__ double red[4];

    const int bh  = blockIdx.x;        // 0..31
    const int h   = bh & 7;
    const int tid = threadIdx.x;
    const int t   = blockIdx.y * 256 + tid;

    const float* mp = means + h * (NC * DD);
    for (int i = tid; i < NC * DD; i += 256) mS[i] = mp[i];
    __syncthreads();
    if (tid < NC) {
        double s = 0.0;
        for (int d = 0; d < DD; d++) { double m = (double)mS[tid * DD + d]; s += m * m; }
        mn2[tid] = s;
    }
    __syncthreads();

    float rr[DD];
    const float* src = qk + ((size_t)bh * TT + t) * DD;
#pragma unroll
    for (int i = 0; i < DD / 4; i++) {
        float4 t4 = ((const float4*)src)[i];
        rr[4*i+0] = t4.x; rr[4*i+1] = t4.y; rr[4*i+2] = t4.z; rr[4*i+3] = t4.w;
    }
    double ss = 0.0;
#pragma unroll
    for (int i = 0; i < DD; i++) ss += (double)rr[i] * (double)rr[i];
    const double inv = 1.0 / fmax(sqrt(ss), 1e-12);

    double dmax = -1e300; int cbest = 0;
    double* dbase = dists + (size_t)bh * NC * TT + t;
    for (int c0 = 0; c0 < NC; c0 += 8) {
        double a[8] = {0, 0, 0, 0, 0, 0, 0, 0};
        for (int d0 = 0; d0 < DD; d0 += 4) {
            const double r0 = (double)rr[d0+0], r1 = (double)rr[d0+1];
            const double r2 = (double)rr[d0+2], r3 = (double)rr[d0+3];
#pragma unroll
            for (int cc = 0; cc < 8; cc++) {
                float4 m4 = *(const float4*)(mS + (c0 + cc) * DD + d0);
                a[cc] += r0 * (double)m4.x + r1 * (double)m4.y
                       + r2 * (double)m4.z + r3 * (double)m4.w;
            }
        }
#pragma unroll
        for (int cc = 0; cc < 8; cc++) {
            const double dv = a[cc] * inv;
            dbase[(size_t)(c0 + cc) * TT] = dv;
            if (dv > dmax) { dmax = dv; cbest = c0 + cc; }
        }
    }

    double lt = (ss * inv * inv) + mn2[cbest] - 2.0 * dmax;
#pragma unroll
    for (int o = 32; o; o >>= 1) lt += __shfl_xor(lt, o);
    if ((tid & 63) == 0) red[tid >> 6] = lt;
    __syncthreads();
    if (tid == 0) atomicAdd(lossa, red[0] + red[1] + red[2] + red[3]);
}

// ---------------------------------------------------------------------------
// Kernel 2: exact top-128 per (bh,c) over 8192 fp64 dists, emitted sorted
// ascending by token index (matches jax.lax.top_k stability + jnp.sort).
// ---------------------------------------------------------------------------
__global__ __launch_bounds__(256) void k_topk(
    const double* __restrict__ dists, int* __restrict__ indices)
{
    __shared__ int wred[4];
    __shared__ int scan_gt[256];
    __shared__ int scan_eq[256];

    const int bhc = blockIdx.x;            // bh*64 + c
    const int tid = threadIdx.x;
    const double* row = dists + (size_t)bhc * TT;

    // 32 contiguous tokens per thread, keys monotonic-mapped to u64
    unsigned long long key[32];
    {
        const ulonglong2* p = (const ulonglong2*)(row + tid * 32);
#pragma unroll
        for (int i = 0; i < 16; i++) {
            ulonglong2 u2 = p[i];
            long long a = (long long)u2.x, b = (long long)u2.y;
            key[2*i+0] = (a < 0) ? ~(unsigned long long)a
                                 : ((unsigned long long)a | 0x8000000000000000ULL);
            key[2*i+1] = (b < 0) ? ~(unsigned long long)b
                                 : ((unsigned long long)b | 0x8000000000000000ULL);
        }
    }

    // bitwise search for 128th-largest key (exact)
    unsigned long long thr = 0ULL;
    for (int b = 63; b >= 0; b--) {
        const unsigned long long cand = thr | (1ULL << b);
        int c = 0;
#pragma unroll
        for (int i = 0; i < 32; i++) c += (key[i] >= cand) ? 1 : 0;
#pragma unroll
        for (int o = 32; o; o >>= 1) c += __shfl_xor(c, o);
        if ((tid & 63) == 0) wred[tid >> 6] = c;
        __syncthreads();
        const int tot = wred[0] + wred[1] + wred[2] + wred[3];
        __syncthreads();
        if (tot >= WW) thr = cand;
    }

    int cgt = 0, ceq = 0;
#pragma unroll
    for (int i = 0; i < 32; i++) {
        cgt += (key[i] > thr) ? 1 : 0;
        ceq += (key[i] == thr) ? 1 : 0;
    }
    scan_gt[tid] = cgt; scan_eq[tid] = ceq;
    __syncthreads();
    for (int o = 1; o < 256; o <<= 1) {
        int a = 0, b = 0;
        if (tid >= o) { a = scan_gt[tid - o]; b = scan_eq[tid - o]; }
        __syncthreads();
        scan_gt[tid] += a; scan_eq[tid] += b;
        __syncthreads();
    }
    const int pgt = scan_gt[tid] - cgt;       // exclusive prefixes
    const int peq = scan_eq[tid] - ceq;
    const int rneed = WW - scan_gt[255];      // ties needed (>=1)

    int* outp = indices + bhc * WW;
    int g = 0, e = 0;
#pragma unroll
    for (int i = 0; i < 32; i++) {
        const int tok = tid * 32 + i;
        if (key[i] > thr) {
            const int tie_before = (peq + e < rneed) ? (peq + e) : rneed;
            outp[pgt + g + tie_before] = tok;
            g++;
        } else if (key[i] == thr) {
            if (peq + e < rneed) outp[pgt + g + peq + e] = tok;
            e++;
        }
    }
}

// ---------------------------------------------------------------------------
// Kernel 3: per-(bh,c) local attention with relative-shift bias, MFMA bf16.
// One wg = 256 threads = 4 waves; wave w owns rows [32w,32w+32).
// ---------------------------------------------------------------------------
__global__ __launch_bounds__(256) void k_attn(
    const float* __restrict__ qk, const float* __restrict__ vin,
    const float* __restrict__ rel_w, const int* __restrict__ indices,
    float* __restrict__ out, float* __restrict__ den)
{
    __shared__ __attribute__((aligned(16))) __bf16 qs[128 * 72];   // raw q rows (later reused as v^T)
    __shared__ __attribute__((aligned(16))) __bf16 rs[128 * 136];  // R matrix, later P matrix
    __shared__ float invs[128];
    __shared__ int   idxs[128];

    const int tid  = threadIdx.x;
    const int lane = tid & 63;
    const int wv   = tid >> 6;
    const int lo   = lane & 15;
    const int quad = lane >> 4;
    const int rbase = wv * 32;

    const int bhc = blockIdx.x;
    const int bh  = bhc >> 6;
    const int h   = bh & 7;

    if (tid < 128) idxs[tid] = indices[bhc * WW + tid];
    __syncthreads();

    // ---- gather q rows -> bf16 LDS, compute 1/||q|| per row ----
    {
        const int r = tid >> 1, half = tid & 1;
        const float* src = qk + ((size_t)bh * TT + idxs[r]) * DD + half * 32;
        float buf[32];
#pragma unroll
        for (int i = 0; i < 8; i++) {
            float4 t4 = ((const float4*)src)[i];
            buf[4*i+0] = t4.x; buf[4*i+1] = t4.y; buf[4*i+2] = t4.z; buf[4*i+3] = t4.w;
        }
        float ssq = 0.f;
#pragma unroll
        for (int i = 0; i < 32; i++) ssq += buf[i] * buf[i];
        ssq += __shfl_xor(ssq, 1);
        if (!half) invs[r] = 1.0f / fmaxf(sqrtf(ssq), 1e-12f);
#pragma unroll
        for (int i = 0; i < 32; i++) qs[r * 72 + half * 32 + i] = (__bf16)buf[i];
    }
    __syncthreads();

    f32x4 acc[2][8];

    // ---- R = Q * W^T  (R[i][r] = sum_d q[i][d]*rel_w[r][h][d]) ----
#pragma unroll
    for (int rt = 0; rt < 2; rt++)
#pragma unroll
        for (int nt = 0; nt < 8; nt++) acc[rt][nt] = (f32x4){0.f, 0.f, 0.f, 0.f};

#pragma unroll
    for (int k0 = 0; k0 < 64; k0 += 32) {
        bf16x8 qa[2];
#pragma unroll
        for (int rt = 0; rt < 2; rt++)
            qa[rt] = *(const bf16x8*)(qs + (rbase + rt * 16 + lo) * 72 + k0 + quad * 8);
#pragma unroll
        for (int nt = 0; nt < 8; nt++) {
            const float* wp = rel_w + (size_t)((nt * 16 + lo) * 8 + h) * 64 + k0 + quad * 8;
            float4 w0 = ((const float4*)wp)[0];
            float4 w1 = ((const float4*)wp)[1];
            bf16x8 wb;
            wb[0] = (__bf16)w0.x; wb[1] = (__bf16)w0.y; wb[2] = (__bf16)w0.z; wb[3] = (__bf16)w0.w;
            wb[4] = (__bf16)w1.x; wb[5] = (__bf16)w1.y; wb[6] = (__bf16)w1.z; wb[7] = (__bf16)w1.w;
#pragma unroll
            for (int rt = 0; rt < 2; rt++)
                acc[rt][nt] = MFMA(qa[rt], wb, acc[rt][nt]);
        }
    }
    // write R (wave-local rows)
#pragma unroll
    for (int rt = 0; rt < 2; rt++)
#pragma unroll
        for (int nt = 0; nt < 8; nt++)
#pragma unroll
            for (int r = 0; r < 4; r++)
                rs[(rbase + rt * 16 + quad * 4 + r) * 136 + nt * 16 + lo] = (__bf16)acc[rt][nt][r];
    __syncthreads();

    // ---- dots = (Q*Q^T) * inv_j * scale ----
#pragma unroll
    for (int rt = 0; rt < 2; rt++)
#pragma unroll
        for (int nt = 0; nt < 8; nt++) acc[rt][nt] = (f32x4){0.f, 0.f, 0.f, 0.f};

#pragma unroll
    for (int k0 = 0; k0 < 64; k0 += 32) {
        bf16x8 qa[2];
#pragma unroll
        for (int rt = 0; rt < 2; rt++)
            qa[rt] = *(const bf16x8*)(qs + (rbase + rt * 16 + lo) * 72 + k0 + quad * 8);
#pragma unroll
        for (int nt = 0; nt < 8; nt++) {
            bf16x8 qb = *(const bf16x8*)(qs + (nt * 16 + lo) * 72 + k0 + quad * 8);
#pragma unroll
            for (int rt = 0; rt < 2; rt++)
                acc[rt][nt] = MFMA(qa[rt], qb, acc[rt][nt]);
        }
    }

    float inv_j[8];
#pragma unroll
    for (int nt = 0; nt < 8; nt++) inv_j[nt] = invs[nt * 16 + lo];

    // bias (shifted rel), self-mask
#pragma unroll
    for (int rt = 0; rt < 2; rt++)
#pragma unroll
        for (int r = 0; r < 4; r++) {
            const int i = rbase + rt * 16 + quad * 4 + r;
#pragma unroll
            for (int nt = 0; nt < 8; nt++) {
                const int j = nt * 16 + lo;
                float val = acc[rt][nt][r] * inv_j[nt] * SCALE;
                if (j <= i) val += SCALE * (float)rs[i * 136 + (j + 127 - i)];
                if (j == i) val = -50000.0f;
                acc[rt][nt][r] = val;
            }
        }

    // row softmax (rows live in 16-lane groups sharing quad)
#pragma unroll
    for (int rt = 0; rt < 2; rt++)
#pragma unroll
        for (int r = 0; r < 4; r++) {
            float m = -3.0e38f;
#pragma unroll
            for (int nt = 0; nt < 8; nt++) m = fmaxf(m, acc[rt][nt][r]);
#pragma unroll
            for (int msk = 1; msk < 16; msk <<= 1) m = fmaxf(m, __shfl_xor(m, msk));
            float s = 0.f;
#pragma unroll
            for (int nt = 0; nt < 8; nt++) {
                float e = __expf(acc[rt][nt][r] - m);
                acc[rt][nt][r] = e; s += e;
            }
#pragma unroll
            for (int msk = 1; msk < 16; msk <<= 1) s += __shfl_xor(s, msk);
            const float is = 1.0f / s;
            const int i = rbase + rt * 16 + quad * 4 + r;
#pragma unroll
            for (int nt = 0; nt < 8; nt++)
                rs[i * 136 + nt * 16 + lo] = (__bf16)(acc[rt][nt][r] * is);
        }
    __syncthreads();   // everyone done reading qs (dots B-frags) and writing P

    // ---- gather v rows transposed into qs space: vt[d][j] ----
    __bf16* vt = qs;
    {
        const int r = tid >> 1, half = tid & 1;
        const float* src = vin + ((size_t)bh * TT + idxs[r]) * DD + half * 32;
#pragma unroll
        for (int i = 0; i < 8; i++) {
            float4 t4 = ((const float4*)src)[i];
            vt[(half * 32 + 4*i + 0) * 136 + r] = (__bf16)t4.x;
            vt[(half * 32 + 4*i + 1) * 136 + r] = (__bf16)t4.y;
            vt[(half * 32 + 4*i + 2) * 136 + r] = (__bf16)t4.z;
            vt[(half * 32 + 4*i + 3) * 136 + r] = (__bf16)t4.w;
        }
    }
    __syncthreads();

    // ---- bo = P * V ----
    f32x4 accO[2][4];
#pragma unroll
    for (int rt = 0; rt < 2; rt++)
#pragma unroll
        for (int nt = 0; nt < 4; nt++) accO[rt][nt] = (f32x4){0.f, 0.f, 0.f, 0.f};

#pragma unroll
    for (int k0 = 0; k0 < 128; k0 += 32) {
        bf16x8 pa[2];
#pragma unroll
        for (int rt = 0; rt < 2; rt++)
            pa[rt] = *(const bf16x8*)(rs + (rbase + rt * 16 + lo) * 136 + k0 + quad * 8);
#pragma unroll
        for (int nt = 0; nt < 4; nt++) {
            bf16x8 vb = *(const bf16x8*)(vt + (nt * 16 + lo) * 136 + k0 + quad * 8);
#pragma unroll
            for (int rt = 0; rt < 2; rt++)
                accO[rt][nt] = MFMA(pa[rt], vb, accO[rt][nt]);
        }
    }

    // ---- scatter-add ----
#pragma unroll
    for (int rt = 0; rt < 2; rt++)
#pragma unroll
        for (int r = 0; r < 4; r++) {
            const int i = rbase + rt * 16 + quad * 4 + r;
            float* obase = out + ((size_t)bh * TT + idxs[i]) * DD;
#pragma unroll
            for (int nt = 0; nt < 4; nt++)
                atomicAdd(obase + nt * 16 + lo, accO[rt][nt][r]);
        }
    if (tid < 128) atomicAdd(den + (size_t)bh * TT + idxs[tid], 1.0f);
}

// ---------------------------------------------------------------------------
// Kernel 4: out = num / (den + 1e-5), plus loss scalar
// ---------------------------------------------------------------------------
__global__ __launch_bounds__(256) void k_fin(
    float* __restrict__ out, const float* __restrict__ den,
    const double* __restrict__ lossa)
{
    const size_t i = (size_t)blockIdx.x * 256 + threadIdx.x;   // float4 index
    float4 vv = ((const float4*)out)[i];
    const float r = 1.0f / (den[i >> 4] + 1e-5f);
    vv.x *= r; vv.y *= r; vv.z *= r; vv.w *= r;
    ((float4*)out)[i] = vv;
    if (i == 0) out[16777216] = (float)(lossa[0] * (0.0001 / 16777216.0));
}

// ---------------------------------------------------------------------------
extern "C" void kernel_launch(void* const* d_in, const int* in_sizes, int n_in,
                              void* d_out, int out_size, void* d_ws, size_t ws_size,
                              hipStream_t stream) {
    (void)in_sizes; (void)n_in; (void)ws_size;
    const float* qk    = (const float*)d_in[0];
    const float* v     = (const float*)d_in[1];
    const float* means = (const float*)d_in[2];
    const float* rel_w = (const float*)d_in[3];
    float* out = (float*)d_out;

    // ws layout: [dists fp64 134MB][den 1MB][loss 8B][indices 1MB]
    char* ws = (char*)d_ws;
    const size_t DISTS_B = (size_t)BHN * NC * TT * 8;       // 134217728
    const size_t DEN_B   = (size_t)BHN * TT * 4;            // 1048576
    double* dists  = (double*)ws;
    float*  den    = (float*)(ws + DISTS_B);
    double* lossa  = (double*)(ws + DISTS_B + DEN_B);
    int*    idx    = (int*)(ws + DISTS_B + DEN_B + 8);

    hipMemsetAsync(d_out, 0, (size_t)out_size * sizeof(float), stream);
    hipMemsetAsync(ws + DISTS_B, 0, DEN_B + 8, stream);

    k_dists<<<dim3(BHN, TT / 256), 256, 0, stream>>>(qk, means, dists, lossa);
    k_topk<<<BHN * NC, 256, 0, stream>>>(dists, idx);
    k_attn<<<BHN * NC, 256, 0, stream>>>(qk, v, rel_w, idx, out, den);
    k_fin<<<16777216 / 4 / 256, 256, 0, stream>>>(out, den, lossa);
}

// Round 2
// 461.076 us; speedup vs baseline: 1.1449x; 1.1449x over previous
//
#include <hip/hip_runtime.h>
#include <hip/hip_bf16.h>
#include <math.h>

// Problem constants (b=4,h=8,t=8192,d=64, c=64 clusters, wsz=128)
#define NB 4
#define NH 8
#define TT 8192
#define DD 64
#define NC 64
#define WW 128
#define BHN 32            // NB*NH
#define SCALE 0.125f      // d^-0.5

typedef __bf16 bf16x8 __attribute__((ext_vector_type(8)));
typedef float  f32x4  __attribute__((ext_vector_type(4)));
typedef unsigned long long u64;

#define MFMA(a, b, c) __builtin_amdgcn_mfma_f32_16x16x32_bf16((a), (b), (c), 0, 0, 0)

__device__ __forceinline__ u64 sortable(double d) {
    long long b = __double_as_longlong(d);
    return (b < 0) ? ~(u64)b : ((u64)b | 0x8000000000000000ULL);
}

// ---------------------------------------------------------------------------
// Kernel 0: means fp32 -> fp64 (so k_dists can s_load fp64 operands directly)
// ---------------------------------------------------------------------------
__global__ __launch_bounds__(256) void k_prep(
    const float* __restrict__ means, double* __restrict__ means64)
{
    const int i = blockIdx.x * 256 + threadIdx.x;   // 32768 total
    means64[i] = (double)means[i];
}

// ---------------------------------------------------------------------------
// Kernel 1: routing dists in fp64, stored as sortable u64 keys.
// means64 indexed wave-uniformly -> SMEM s_loads, v_fma_f64 with SGPR operand.
// ---------------------------------------------------------------------------
__global__ __launch_bounds__(256) void k_dists(
    const float* __restrict__ qk, const double* __restrict__ means64,
    u64* __restrict__ keys, double* __restrict__ lossa)
{
    __shared__ double mn2[NC];
    __shared__ double red[4];

    const int bh  = blockIdx.x;        // 0..31
    const int h   = bh & 7;
    const int tid = threadIdx.x;
    const int t   = blockIdx.y * 256 + tid;
    const double* __restrict__ mp = means64 + (size_t)h * NC * DD;

    if (tid < NC) {
        double s = 0.0;
        for (int d = 0; d < DD; d++) { const double m = mp[tid * DD + d]; s = fma(m, m, s); }
        mn2[tid] = s;
    }

    float rr[DD];
    const float* src = qk + ((size_t)bh * TT + t) * DD;
#pragma unroll
    for (int i = 0; i < DD / 4; i++) {
        float4 t4 = ((const float4*)src)[i];
        rr[4*i+0] = t4.x; rr[4*i+1] = t4.y; rr[4*i+2] = t4.z; rr[4*i+3] = t4.w;
    }
    double ss = 0.0;
#pragma unroll
    for (int i = 0; i < DD; i++) ss = fma((double)rr[i], (double)rr[i], ss);
    const double inv = 1.0 / fmax(sqrt(ss), 1e-12);

    double dmax = -1e300; int cbest = 0;
    u64* kb = keys + (size_t)bh * NC * TT + t;
    for (int c0 = 0; c0 < NC; c0 += 8) {
        double a[8] = {0, 0, 0, 0, 0, 0, 0, 0};
#pragma unroll
        for (int d0 = 0; d0 < DD; d0 += 4) {
            const double r0 = (double)rr[d0+0], r1 = (double)rr[d0+1];
            const double r2 = (double)rr[d0+2], r3 = (double)rr[d0+3];
#pragma unroll
            for (int cc = 0; cc < 8; cc++) {
                const double* m = mp + (c0 + cc) * DD + d0;   // uniform -> s_load
                a[cc] = fma(r0, m[0], a[cc]);
                a[cc] = fma(r1, m[1], a[cc]);
                a[cc] = fma(r2, m[2], a[cc]);
                a[cc] = fma(r3, m[3], a[cc]);
            }
        }
#pragma unroll
        for (int cc = 0; cc < 8; cc++) {
            const double dv = a[cc] * inv;
            kb[(size_t)(c0 + cc) * TT] = sortable(dv);
            if (dv > dmax) { dmax = dv; cbest = c0 + cc; }
        }
    }

    __syncthreads();
    double lt = fma(ss, inv * inv, mn2[cbest] - 2.0 * dmax);
#pragma unroll
    for (int o = 32; o; o >>= 1) lt += __shfl_xor(lt, o);
    if ((tid & 63) == 0) red[tid >> 6] = lt;
    __syncthreads();
    if (tid == 0) atomicAdd(lossa, red[0] + red[1] + red[2] + red[3]);
}

// ---------------------------------------------------------------------------
// Kernel 2: top-128 per (bh,c) via histogram radix select (11 bits/level).
// Emitted sorted ascending by token index; ties take lowest indices (matches
// stable top_k + sort).
// ---------------------------------------------------------------------------
__global__ __launch_bounds__(256) void k_topk(
    const u64* __restrict__ keys, int* __restrict__ indices)
{
    __shared__ unsigned int hist[4][2048];   // 32 KB, per-wave copies
    __shared__ int wsum[8];
    __shared__ int bc_bin, bc_rank, bc_cnt;

    const int bhc = blockIdx.x, tid = threadIdx.x;
    const int wv = tid >> 6, lane = tid & 63;

    u64 key[32];
    {
        const ulonglong2* p = (const ulonglong2*)(keys + (size_t)bhc * TT + tid * 32);
#pragma unroll
        for (int i = 0; i < 16; i++) { ulonglong2 u = p[i]; key[2*i] = u.x; key[2*i+1] = u.y; }
    }

    u64 thr = 0;
    int need = 128, gshift = 53, prevShift = 0;

    for (int level = 0; level < 6; level++) {
        const int shift = (level < 5) ? (53 - 11 * level) : 0;
        for (int i = tid; i < 2048; i += 256) {
            hist[0][i] = 0; hist[1][i] = 0; hist[2][i] = 0; hist[3][i] = 0;
        }
        __syncthreads();
        unsigned int* hw = hist[wv];
        if (level == 0) {
#pragma unroll
            for (int i = 0; i < 32; i++)
                atomicAdd(&hw[(unsigned int)(key[i] >> 53)], 1u);
        } else {
            const u64 pv = thr >> prevShift;
#pragma unroll
            for (int i = 0; i < 32; i++)
                if ((key[i] >> prevShift) == pv)
                    atomicAdd(&hw[(unsigned int)(key[i] >> shift) & 2047u], 1u);
        }
        __syncthreads();

        // descending-order scan: thread t covers bins [2047-8t-7 .. 2047-8t]
        int s8[8]; int loc = 0;
        const int bhi = 2047 - 8 * tid;
#pragma unroll
        for (int j = 0; j < 8; j++) {
            const int b = bhi - j;
            const int c = hist[0][b] + hist[1][b] + hist[2][b] + hist[3][b];
            s8[j] = c; loc += c;
        }
        int incl = loc;
#pragma unroll
        for (int o = 1; o < 64; o <<= 1) {
            const int v = __shfl_up(incl, o);
            if (lane >= o) incl += v;
        }
        if (lane == 63) wsum[wv] = incl;
        __syncthreads();
        int above = incl - loc;
        for (int wj = 0; wj < wv; wj++) above += wsum[wj];
        if (above < need && above + loc >= need) {
            int cum = above;
#pragma unroll
            for (int j = 0; j < 8; j++) {
                if (cum + s8[j] >= need) { bc_bin = bhi - j; bc_rank = cum; bc_cnt = s8[j]; break; }
                cum += s8[j];
            }
        }
        __syncthreads();
        thr |= ((u64)(unsigned int)bc_bin) << shift;
        need -= bc_rank;
        gshift = shift;
        prevShift = shift;
        if (bc_cnt == need || shift == 0) break;
    }

    // ordered emission
    const u64 tg = thr >> gshift;
    int cgt = 0, ceq = 0;
#pragma unroll
    for (int i = 0; i < 32; i++) {
        const u64 kg = key[i] >> gshift;
        cgt += (kg > tg) ? 1 : 0;
        ceq += (kg == tg) ? 1 : 0;
    }
    int ig = cgt, ie = ceq;
#pragma unroll
    for (int o = 1; o < 64; o <<= 1) {
        const int vg = __shfl_up(ig, o);
        const int ve = __shfl_up(ie, o);
        if (lane >= o) { ig += vg; ie += ve; }
    }
    if (lane == 63) { wsum[wv] = ig; wsum[4 + wv] = ie; }
    __syncthreads();
    int pgt = ig - cgt, peq = ie - ceq;
    for (int wj = 0; wj < wv; wj++) { pgt += wsum[wj]; peq += wsum[4 + wj]; }

    const int rneed = need;
    int* outp = indices + bhc * WW;
    int g = 0, e = 0;
#pragma unroll
    for (int i = 0; i < 32; i++) {
        const int tok = tid * 32 + i;
        const u64 kg = key[i] >> gshift;
        if (kg > tg) {
            const int tb = (peq + e < rneed) ? (peq + e) : rneed;
            outp[pgt + g + tb] = tok;
            g++;
        } else if (kg == tg) {
            if (peq + e < rneed) outp[pgt + g + peq + e] = tok;
            e++;
        }
    }
}

// ---------------------------------------------------------------------------
// Kernel 3: per-(bh,c) local attention, MFMA bf16. 512 threads = 8 waves;
// wave w owns rows [16w,16w+16). V gather prefetched into registers.
// ---------------------------------------------------------------------------
__global__ __launch_bounds__(512) void k_attn(
    const float* __restrict__ qk, const float* __restrict__ vin,
    const float* __restrict__ rel_w, const int* __restrict__ indices,
    float* __restrict__ out, float* __restrict__ den)
{
    __shared__ __attribute__((aligned(16))) __bf16 qs[128 * 72];   // q rows; later v^T
    __shared__ __attribute__((aligned(16))) __bf16 rs[128 * 136];  // R; later P
    __shared__ float invs[128];
    __shared__ int   idxs[128];

    const int tid  = threadIdx.x;
    const int lane = tid & 63;
    const int wv   = tid >> 6;
    const int lo   = lane & 15;
    const int quad = lane >> 4;
    const int rbase = wv * 16;

    const int bhc = blockIdx.x;
    const int bh  = bhc >> 6;
    const int h   = bh & 7;

    if (tid < 128) idxs[tid] = indices[bhc * WW + tid];
    __syncthreads();

    // ---- q gather (issued first), v gather prefetch (held in regs) ----
    const int r  = tid >> 2;          // row 0..127
    const int qp = tid & 3;           // 16-float segment
    const size_t rowoff = ((size_t)bh * TT + idxs[r]) * DD + qp * 16;
    float4 q0, q1, q2, q3, vreg[4];
    {
        const float4* qsrc = (const float4*)(qk + rowoff);
        q0 = qsrc[0]; q1 = qsrc[1]; q2 = qsrc[2]; q3 = qsrc[3];
        const float4* vsrc = (const float4*)(vin + rowoff);
        vreg[0] = vsrc[0]; vreg[1] = vsrc[1]; vreg[2] = vsrc[2]; vreg[3] = vsrc[3];
    }
    {
        float ssq = q0.x*q0.x + q0.y*q0.y + q0.z*q0.z + q0.w*q0.w
                  + q1.x*q1.x + q1.y*q1.y + q1.z*q1.z + q1.w*q1.w
                  + q2.x*q2.x + q2.y*q2.y + q2.z*q2.z + q2.w*q2.w
                  + q3.x*q3.x + q3.y*q3.y + q3.z*q3.z + q3.w*q3.w;
        ssq += __shfl_xor(ssq, 1);
        ssq += __shfl_xor(ssq, 2);
        if (qp == 0) invs[r] = 1.0f / fmaxf(sqrtf(ssq), 1e-12f);
        __bf16* dst = qs + r * 72 + qp * 16;
        dst[0]=(__bf16)q0.x; dst[1]=(__bf16)q0.y; dst[2]=(__bf16)q0.z; dst[3]=(__bf16)q0.w;
        dst[4]=(__bf16)q1.x; dst[5]=(__bf16)q1.y; dst[6]=(__bf16)q1.z; dst[7]=(__bf16)q1.w;
        dst[8]=(__bf16)q2.x; dst[9]=(__bf16)q2.y; dst[10]=(__bf16)q2.z; dst[11]=(__bf16)q2.w;
        dst[12]=(__bf16)q3.x; dst[13]=(__bf16)q3.y; dst[14]=(__bf16)q3.z; dst[15]=(__bf16)q3.w;
    }
    __syncthreads();

    f32x4 acc[8];

    // ---- R = Q * W^T ----
#pragma unroll
    for (int nt = 0; nt < 8; nt++) acc[nt] = (f32x4){0.f, 0.f, 0.f, 0.f};
#pragma unroll
    for (int k0 = 0; k0 < 64; k0 += 32) {
        bf16x8 qa = *(const bf16x8*)(qs + (rbase + lo) * 72 + k0 + quad * 8);
#pragma unroll
        for (int nt = 0; nt < 8; nt++) {
            const float* wp = rel_w + (size_t)((nt * 16 + lo) * 8 + h) * 64 + k0 + quad * 8;
            float4 w0 = ((const float4*)wp)[0];
            float4 w1 = ((const float4*)wp)[1];
            bf16x8 wb;
            wb[0]=(__bf16)w0.x; wb[1]=(__bf16)w0.y; wb[2]=(__bf16)w0.z; wb[3]=(__bf16)w0.w;
            wb[4]=(__bf16)w1.x; wb[5]=(__bf16)w1.y; wb[6]=(__bf16)w1.z; wb[7]=(__bf16)w1.w;
            acc[nt] = MFMA(qa, wb, acc[nt]);
        }
    }
#pragma unroll
    for (int nt = 0; nt < 8; nt++)
#pragma unroll
        for (int rg = 0; rg < 4; rg++)
            rs[(rbase + quad * 4 + rg) * 136 + nt * 16 + lo] = (__bf16)acc[nt][rg];

    // ---- dots = (Q*Q^T) * inv_j * scale ----
#pragma unroll
    for (int nt = 0; nt < 8; nt++) acc[nt] = (f32x4){0.f, 0.f, 0.f, 0.f};
#pragma unroll
    for (int k0 = 0; k0 < 64; k0 += 32) {
        bf16x8 qa = *(const bf16x8*)(qs + (rbase + lo) * 72 + k0 + quad * 8);
#pragma unroll
        for (int nt = 0; nt < 8; nt++) {
            bf16x8 qb = *(const bf16x8*)(qs + (nt * 16 + lo) * 72 + k0 + quad * 8);
            acc[nt] = MFMA(qa, qb, acc[nt]);
        }
    }

    float inv_j[8];
#pragma unroll
    for (int nt = 0; nt < 8; nt++) inv_j[nt] = invs[nt * 16 + lo];

    // bias (shifted rel) + self-mask
#pragma unroll
    for (int rg = 0; rg < 4; rg++) {
        const int i = rbase + quad * 4 + rg;
#pragma unroll
        for (int nt = 0; nt < 8; nt++) {
            const int j = nt * 16 + lo;
            float val = acc[nt][rg] * inv_j[nt] * SCALE;
            if (j <= i) val += SCALE * (float)rs[i * 136 + (j + 127 - i)];
            if (j == i) val = -50000.0f;
            acc[nt][rg] = val;
        }
    }

    // row softmax (16 lanes of same quad share a row)
#pragma unroll
    for (int rg = 0; rg < 4; rg++) {
        float m = -3.0e38f;
#pragma unroll
        for (int nt = 0; nt < 8; nt++) m = fmaxf(m, acc[nt][rg]);
#pragma unroll
        for (int msk = 1; msk < 16; msk <<= 1) m = fmaxf(m, __shfl_xor(m, msk));
        float s = 0.f;
#pragma unroll
        for (int nt = 0; nt < 8; nt++) {
            const float e = __expf(acc[nt][rg] - m);
            acc[nt][rg] = e; s += e;
        }
#pragma unroll
        for (int msk = 1; msk < 16; msk <<= 1) s += __shfl_xor(s, msk);
        const float is = 1.0f / s;
        const int i = rbase + quad * 4 + rg;
#pragma unroll
        for (int nt = 0; nt < 8; nt++)
            rs[i * 136 + nt * 16 + lo] = (__bf16)(acc[nt][rg] * is);
    }
    __syncthreads();   // all QQ^T reads of qs done; P complete

    // ---- v (from regs) transposed into qs space: vt[d][j] ----
    __bf16* vt = qs;
#pragma unroll
    for (int i = 0; i < 4; i++) {
        vt[(qp * 16 + 4*i + 0) * 136 + r] = (__bf16)vreg[i].x;
        vt[(qp * 16 + 4*i + 1) * 136 + r] = (__bf16)vreg[i].y;
        vt[(qp * 16 + 4*i + 2) * 136 + r] = (__bf16)vreg[i].z;
        vt[(qp * 16 + 4*i + 3) * 136 + r] = (__bf16)vreg[i].w;
    }
    __syncthreads();

    // ---- bo = P * V ----
    f32x4 accO[4];
#pragma unroll
    for (int nt = 0; nt < 4; nt++) accO[nt] = (f32x4){0.f, 0.f, 0.f, 0.f};
#pragma unroll
    for (int k0 = 0; k0 < 128; k0 += 32) {
        bf16x8 pa = *(const bf16x8*)(rs + (rbase + lo) * 136 + k0 + quad * 8);
#pragma unroll
        for (int nt = 0; nt < 4; nt++) {
            bf16x8 vb = *(const bf16x8*)(vt + (nt * 16 + lo) * 136 + k0 + quad * 8);
            accO[nt] = MFMA(pa, vb, accO[nt]);
        }
    }

    // ---- scatter-add ----
#pragma unroll
    for (int rg = 0; rg < 4; rg++) {
        const int i = rbase + quad * 4 + rg;
        float* obase = out + ((size_t)bh * TT + idxs[i]) * DD;
#pragma unroll
        for (int nt = 0; nt < 4; nt++)
            atomicAdd(obase + nt * 16 + lo, accO[nt][rg]);
    }
    if (tid < 128) atomicAdd(den + (size_t)bh * TT + idxs[tid], 1.0f);
}

// ---------------------------------------------------------------------------
// Kernel 4: out = num / (den + 1e-5), plus loss scalar
// ---------------------------------------------------------------------------
__global__ __launch_bounds__(256) void k_fin(
    float* __restrict__ out, const float* __restrict__ den,
    const double* __restrict__ lossa)
{
    const size_t i = (size_t)blockIdx.x * 256 + threadIdx.x;   // float4 index
    float4 vv = ((const float4*)out)[i];
    const float r = 1.0f / (den[i >> 4] + 1e-5f);
    vv.x *= r; vv.y *= r; vv.z *= r; vv.w *= r;
    ((float4*)out)[i] = vv;
    if (i == 0) out[16777216] = (float)(lossa[0] * (0.0001 / 16777216.0));
}

// ---------------------------------------------------------------------------
extern "C" void kernel_launch(void* const* d_in, const int* in_sizes, int n_in,
                              void* d_out, int out_size, void* d_ws, size_t ws_size,
                              hipStream_t stream) {
    (void)in_sizes; (void)n_in; (void)ws_size;
    const float* qk    = (const float*)d_in[0];
    const float* v     = (const float*)d_in[1];
    const float* means = (const float*)d_in[2];
    const float* rel_w = (const float*)d_in[3];
    float* out = (float*)d_out;

    // ws layout: [keys u64 134MB][den 1MB][loss 8B][idx 1MB (means64 overlaps
    // its first 256KB: read only by k_dists, overwritten by k_topk after)]
    char* ws = (char*)d_ws;
    const size_t KEYS_B = (size_t)BHN * NC * TT * 8;        // 134217728
    const size_t DEN_B  = (size_t)BHN * TT * 4;             // 1048576
    u64*    keys   = (u64*)ws;
    float*  den    = (float*)(ws + KEYS_B);
    double* lossa  = (double*)(ws + KEYS_B + DEN_B);
    int*    idx    = (int*)(ws + KEYS_B + DEN_B + 8);
    double* means64 = (double*)(ws + KEYS_B + DEN_B + 8);   // aliases idx (sequentially safe)

    hipMemsetAsync(d_out, 0, (size_t)out_size * sizeof(float), stream);
    hipMemsetAsync(ws + KEYS_B, 0, DEN_B + 8, stream);

    k_prep<<<NH * NC * DD / 256, 256, 0, stream>>>(means, means64);
    k_dists<<<dim3(BHN, TT / 256), 256, 0, stream>>>(qk, means64, keys, lossa);
    k_topk<<<BHN * NC, 256, 0, stream>>>(keys, idx);
    k_attn<<<BHN * NC, 512, 0, stream>>>(qk, v, rel_w, idx, out, den);
    k_fin<<<16777216 / 4 / 256, 256, 0, stream>>>(out, den, lossa);
}

// Round 3
// 448.500 us; speedup vs baseline: 1.1770x; 1.0280x over previous
//
#include <hip/hip_runtime.h>
#include <hip/hip_bf16.h>
#include <math.h>

// Problem constants (b=4,h=8,t=8192,d=64, c=64 clusters, wsz=128)
#define NB 4
#define NH 8
#define TT 8192
#define DD 64
#define NC 64
#define WW 128
#define BHN 32            // NB*NH
#define SCALE 0.125f      // d^-0.5
#define INVCAP 24         // max tracked clusters per token (Binomial(64,1/64) tail ~0)

typedef __bf16 bf16x8 __attribute__((ext_vector_type(8)));
typedef float  f32x4  __attribute__((ext_vector_type(4)));
typedef unsigned long long u64;

#define MFMA(a, b, c) __builtin_amdgcn_mfma_f32_16x16x32_bf16((a), (b), (c), 0, 0, 0)

__device__ __forceinline__ u64 sortable(double d) {
    long long b = __double_as_longlong(d);
    return (b < 0) ? ~(u64)b : ((u64)b | 0x8000000000000000ULL);
}

// ---------------------------------------------------------------------------
// Kernel 0: means fp32 -> fp64 (so k_dists can s_load fp64 operands directly)
// ---------------------------------------------------------------------------
__global__ __launch_bounds__(256) void k_prep(
    const float* __restrict__ means, double* __restrict__ means64)
{
    const int i = blockIdx.x * 256 + threadIdx.x;   // 32768 total
    means64[i] = (double)means[i];
}

// ---------------------------------------------------------------------------
// Kernel 1: routing dists in fp64, stored as sortable u64 keys.
// ---------------------------------------------------------------------------
__global__ __launch_bounds__(256) void k_dists(
    const float* __restrict__ qk, const double* __restrict__ means64,
    u64* __restrict__ keys, double* __restrict__ lossa)
{
    __shared__ double mn2[NC];
    __shared__ double red[4];

    const int bh  = blockIdx.x;        // 0..31
    const int h   = bh & 7;
    const int tid = threadIdx.x;
    const int t   = blockIdx.y * 256 + tid;
    const double* __restrict__ mp = means64 + (size_t)h * NC * DD;

    if (tid < NC) {
        double s = 0.0;
        for (int d = 0; d < DD; d++) { const double m = mp[tid * DD + d]; s = fma(m, m, s); }
        mn2[tid] = s;
    }

    float rr[DD];
    const float* src = qk + ((size_t)bh * TT + t) * DD;
#pragma unroll
    for (int i = 0; i < DD / 4; i++) {
        float4 t4 = ((const float4*)src)[i];
        rr[4*i+0] = t4.x; rr[4*i+1] = t4.y; rr[4*i+2] = t4.z; rr[4*i+3] = t4.w;
    }
    double ss = 0.0;
#pragma unroll
    for (int i = 0; i < DD; i++) ss = fma((double)rr[i], (double)rr[i], ss);
    const double inv = 1.0 / fmax(sqrt(ss), 1e-12);

    double dmax = -1e300; int cbest = 0;
    u64* kb = keys + (size_t)bh * NC * TT + t;
    for (int c0 = 0; c0 < NC; c0 += 8) {
        double a[8] = {0, 0, 0, 0, 0, 0, 0, 0};
#pragma unroll
        for (int d0 = 0; d0 < DD; d0 += 4) {
            const double r0 = (double)rr[d0+0], r1 = (double)rr[d0+1];
            const double r2 = (double)rr[d0+2], r3 = (double)rr[d0+3];
#pragma unroll
            for (int cc = 0; cc < 8; cc++) {
                const double* m = mp + (c0 + cc) * DD + d0;   // uniform -> s_load
                a[cc] = fma(r0, m[0], a[cc]);
                a[cc] = fma(r1, m[1], a[cc]);
                a[cc] = fma(r2, m[2], a[cc]);
                a[cc] = fma(r3, m[3], a[cc]);
            }
        }
#pragma unroll
        for (int cc = 0; cc < 8; cc++) {
            const double dv = a[cc] * inv;
            kb[(size_t)(c0 + cc) * TT] = sortable(dv);
            if (dv > dmax) { dmax = dv; cbest = c0 + cc; }
        }
    }

    __syncthreads();
    double lt = fma(ss, inv * inv, mn2[cbest] - 2.0 * dmax);
#pragma unroll
    for (int o = 32; o; o >>= 1) lt += __shfl_xor(lt, o);
    if ((tid & 63) == 0) red[tid >> 6] = lt;
    __syncthreads();
    if (tid == 0) atomicAdd(lossa, red[0] + red[1] + red[2] + red[3]);
}

// ---------------------------------------------------------------------------
// Kernel 2: top-128 per (bh,c) via histogram radix select (11 bits/level).
// Emits indices sorted ascending (ties -> lowest index, matching stable
// top_k + sort) AND the inverse map (cnt, inv) used by k_out.
// ---------------------------------------------------------------------------
__global__ __launch_bounds__(256) void k_topk(
    const u64* __restrict__ keys, int* __restrict__ indices,
    unsigned int* __restrict__ cnt, unsigned short* __restrict__ inv)
{
    __shared__ unsigned int hist[4][2048];   // 32 KB, per-wave copies
    __shared__ int wsum[8];
    __shared__ int bc_bin, bc_rank, bc_cnt;

    const int bhc = blockIdx.x, tid = threadIdx.x;
    const int wv = tid >> 6, lane = tid & 63;
    const int bh = bhc >> 6;

    u64 key[32];
    {
        const ulonglong2* p = (const ulonglong2*)(keys + (size_t)bhc * TT + tid * 32);
#pragma unroll
        for (int i = 0; i < 16; i++) { ulonglong2 u = p[i]; key[2*i] = u.x; key[2*i+1] = u.y; }
    }

    u64 thr = 0;
    int need = 128, gshift = 53, prevShift = 0;

    for (int level = 0; level < 6; level++) {
        const int shift = (level < 5) ? (53 - 11 * level) : 0;
        for (int i = tid; i < 2048; i += 256) {
            hist[0][i] = 0; hist[1][i] = 0; hist[2][i] = 0; hist[3][i] = 0;
        }
        __syncthreads();
        unsigned int* hw = hist[wv];
        if (level == 0) {
#pragma unroll
            for (int i = 0; i < 32; i++)
                atomicAdd(&hw[(unsigned int)(key[i] >> 53)], 1u);
        } else {
            const u64 pv = thr >> prevShift;
#pragma unroll
            for (int i = 0; i < 32; i++)
                if ((key[i] >> prevShift) == pv)
                    atomicAdd(&hw[(unsigned int)(key[i] >> shift) & 2047u], 1u);
        }
        __syncthreads();

        // descending-order scan: thread t covers bins [2047-8t-7 .. 2047-8t]
        int s8[8]; int loc = 0;
        const int bhi = 2047 - 8 * tid;
#pragma unroll
        for (int j = 0; j < 8; j++) {
            const int b = bhi - j;
            const int c = hist[0][b] + hist[1][b] + hist[2][b] + hist[3][b];
            s8[j] = c; loc += c;
        }
        int incl = loc;
#pragma unroll
        for (int o = 1; o < 64; o <<= 1) {
            const int v = __shfl_up(incl, o);
            if (lane >= o) incl += v;
        }
        if (lane == 63) wsum[wv] = incl;
        __syncthreads();
        int above = incl - loc;
        for (int wj = 0; wj < wv; wj++) above += wsum[wj];
        if (above < need && above + loc >= need) {
            int cum = above;
#pragma unroll
            for (int j = 0; j < 8; j++) {
                if (cum + s8[j] >= need) { bc_bin = bhi - j; bc_rank = cum; bc_cnt = s8[j]; break; }
                cum += s8[j];
            }
        }
        __syncthreads();
        thr |= ((u64)(unsigned int)bc_bin) << shift;
        need -= bc_rank;
        gshift = shift;
        prevShift = shift;
        if (bc_cnt == need || shift == 0) break;
    }

    // ordered emission + inverse-map build
    const u64 tg = thr >> gshift;
    int cgt = 0, ceq = 0;
#pragma unroll
    for (int i = 0; i < 32; i++) {
        const u64 kg = key[i] >> gshift;
        cgt += (kg > tg) ? 1 : 0;
        ceq += (kg == tg) ? 1 : 0;
    }
    int ig = cgt, ie = ceq;
#pragma unroll
    for (int o = 1; o < 64; o <<= 1) {
        const int vg = __shfl_up(ig, o);
        const int ve = __shfl_up(ie, o);
        if (lane >= o) { ig += vg; ie += ve; }
    }
    if (lane == 63) { wsum[wv] = ig; wsum[4 + wv] = ie; }
    __syncthreads();
    int pgt = ig - cgt, peq = ie - ceq;
    for (int wj = 0; wj < wv; wj++) { pgt += wsum[wj]; peq += wsum[4 + wj]; }

    const int rneed = need;
    int* outp = indices + bhc * WW;
    unsigned int* cntb = cnt + (bh << 13);
    unsigned short* invb = inv + (((size_t)bh << 13) * INVCAP);
    const int cbase = (bhc & 63) * WW;
    int g = 0, e = 0;
#pragma unroll
    for (int i = 0; i < 32; i++) {
        const int tok = tid * 32 + i;
        const u64 kg = key[i] >> gshift;
        if (kg > tg) {
            const int tb = (peq + e < rneed) ? (peq + e) : rneed;
            const int wpos = pgt + g + tb;
            outp[wpos] = tok;
            const unsigned int pos = atomicAdd(&cntb[tok], 1u);
            if (pos < INVCAP) invb[(size_t)tok * INVCAP + pos] = (unsigned short)(cbase + wpos);
            g++;
        } else if (kg == tg) {
            if (peq + e < rneed) {
                const int wpos = pgt + g + peq + e;
                outp[wpos] = tok;
                const unsigned int pos = atomicAdd(&cntb[tok], 1u);
                if (pos < INVCAP) invb[(size_t)tok * INVCAP + pos] = (unsigned short)(cbase + wpos);
            }
            e++;
        }
    }
}

// ---------------------------------------------------------------------------
// Kernel 3: per-(bh,c) local attention, MFMA bf16. 512 threads = 8 waves;
// wave w owns rows [16w,16w+16). Writes bo DENSE (no atomics).
// ---------------------------------------------------------------------------
__global__ __launch_bounds__(512) void k_attn(
    const float* __restrict__ qk, const float* __restrict__ vin,
    const float* __restrict__ rel_w, const int* __restrict__ indices,
    float* __restrict__ bo)
{
    __shared__ __attribute__((aligned(16))) __bf16 qs[128 * 72];   // q rows; later v^T
    __shared__ __attribute__((aligned(16))) __bf16 rs[128 * 136];  // R; later P
    __shared__ float invs[128];
    __shared__ int   idxs[128];

    const int tid  = threadIdx.x;
    const int lane = tid & 63;
    const int wv   = tid >> 6;
    const int lo   = lane & 15;
    const int quad = lane >> 4;
    const int rbase = wv * 16;

    const int bhc = blockIdx.x;
    const int bh  = bhc >> 6;
    const int h   = bh & 7;

    if (tid < 128) idxs[tid] = indices[bhc * WW + tid];
    __syncthreads();

    // ---- q gather (issued first), v gather prefetch (held in regs) ----
    const int r  = tid >> 2;          // row 0..127
    const int qp = tid & 3;           // 16-float segment
    const size_t rowoff = ((size_t)bh * TT + idxs[r]) * DD + qp * 16;
    float4 q0, q1, q2, q3, vreg[4];
    {
        const float4* qsrc = (const float4*)(qk + rowoff);
        q0 = qsrc[0]; q1 = qsrc[1]; q2 = qsrc[2]; q3 = qsrc[3];
        const float4* vsrc = (const float4*)(vin + rowoff);
        vreg[0] = vsrc[0]; vreg[1] = vsrc[1]; vreg[2] = vsrc[2]; vreg[3] = vsrc[3];
    }
    {
        float ssq = q0.x*q0.x + q0.y*q0.y + q0.z*q0.z + q0.w*q0.w
                  + q1.x*q1.x + q1.y*q1.y + q1.z*q1.z + q1.w*q1.w
                  + q2.x*q2.x + q2.y*q2.y + q2.z*q2.z + q2.w*q2.w
                  + q3.x*q3.x + q3.y*q3.y + q3.z*q3.z + q3.w*q3.w;
        ssq += __shfl_xor(ssq, 1);
        ssq += __shfl_xor(ssq, 2);
        if (qp == 0) invs[r] = 1.0f / fmaxf(sqrtf(ssq), 1e-12f);
        __bf16* dst = qs + r * 72 + qp * 16;
        dst[0]=(__bf16)q0.x; dst[1]=(__bf16)q0.y; dst[2]=(__bf16)q0.z; dst[3]=(__bf16)q0.w;
        dst[4]=(__bf16)q1.x; dst[5]=(__bf16)q1.y; dst[6]=(__bf16)q1.z; dst[7]=(__bf16)q1.w;
        dst[8]=(__bf16)q2.x; dst[9]=(__bf16)q2.y; dst[10]=(__bf16)q2.z; dst[11]=(__bf16)q2.w;
        dst[12]=(__bf16)q3.x; dst[13]=(__bf16)q3.y; dst[14]=(__bf16)q3.z; dst[15]=(__bf16)q3.w;
    }
    __syncthreads();

    f32x4 acc[8];

    // ---- R = Q * W^T ----
#pragma unroll
    for (int nt = 0; nt < 8; nt++) acc[nt] = (f32x4){0.f, 0.f, 0.f, 0.f};
#pragma unroll
    for (int k0 = 0; k0 < 64; k0 += 32) {
        bf16x8 qa = *(const bf16x8*)(qs + (rbase + lo) * 72 + k0 + quad * 8);
#pragma unroll
        for (int nt = 0; nt < 8; nt++) {
            const float* wp = rel_w + (size_t)((nt * 16 + lo) * 8 + h) * 64 + k0 + quad * 8;
            float4 w0 = ((const float4*)wp)[0];
            float4 w1 = ((const float4*)wp)[1];
            bf16x8 wb;
            wb[0]=(__bf16)w0.x; wb[1]=(__bf16)w0.y; wb[2]=(__bf16)w0.z; wb[3]=(__bf16)w0.w;
            wb[4]=(__bf16)w1.x; wb[5]=(__bf16)w1.y; wb[6]=(__bf16)w1.z; wb[7]=(__bf16)w1.w;
            acc[nt] = MFMA(qa, wb, acc[nt]);
        }
    }
#pragma unroll
    for (int nt = 0; nt < 8; nt++)
#pragma unroll
        for (int rg = 0; rg < 4; rg++)
            rs[(rbase + quad * 4 + rg) * 136 + nt * 16 + lo] = (__bf16)acc[nt][rg];

    // ---- dots = (Q*Q^T) * inv_j * scale ----
#pragma unroll
    for (int nt = 0; nt < 8; nt++) acc[nt] = (f32x4){0.f, 0.f, 0.f, 0.f};
#pragma unroll
    for (int k0 = 0; k0 < 64; k0 += 32) {
        bf16x8 qa = *(const bf16x8*)(qs + (rbase + lo) * 72 + k0 + quad * 8);
#pragma unroll
        for (int nt = 0; nt < 8; nt++) {
            bf16x8 qb = *(const bf16x8*)(qs + (nt * 16 + lo) * 72 + k0 + quad * 8);
            acc[nt] = MFMA(qa, qb, acc[nt]);
        }
    }

    float inv_j[8];
#pragma unroll
    for (int nt = 0; nt < 8; nt++) inv_j[nt] = invs[nt * 16 + lo];

    // bias (shifted rel) + self-mask
#pragma unroll
    for (int rg = 0; rg < 4; rg++) {
        const int i = rbase + quad * 4 + rg;
#pragma unroll
        for (int nt = 0; nt < 8; nt++) {
            const int j = nt * 16 + lo;
            float val = acc[nt][rg] * inv_j[nt] * SCALE;
            if (j <= i) val += SCALE * (float)rs[i * 136 + (j + 127 - i)];
            if (j == i) val = -50000.0f;
            acc[nt][rg] = val;
        }
    }

    // row softmax (16 lanes of same quad share a row)
#pragma unroll
    for (int rg = 0; rg < 4; rg++) {
        float m = -3.0e38f;
#pragma unroll
        for (int nt = 0; nt < 8; nt++) m = fmaxf(m, acc[nt][rg]);
#pragma unroll
        for (int msk = 1; msk < 16; msk <<= 1) m = fmaxf(m, __shfl_xor(m, msk));
        float s = 0.f;
#pragma unroll
        for (int nt = 0; nt < 8; nt++) {
            const float e = __expf(acc[nt][rg] - m);
            acc[nt][rg] = e; s += e;
        }
#pragma unroll
        for (int msk = 1; msk < 16; msk <<= 1) s += __shfl_xor(s, msk);
        const float is = 1.0f / s;
        const int i = rbase + quad * 4 + rg;
#pragma unroll
        for (int nt = 0; nt < 8; nt++)
            rs[i * 136 + nt * 16 + lo] = (__bf16)(acc[nt][rg] * is);
    }
    __syncthreads();   // all QQ^T reads of qs done; P complete

    // ---- v (from regs) transposed into qs space: vt[d][j] ----
    __bf16* vt = qs;
#pragma unroll
    for (int i = 0; i < 4; i++) {
        vt[(qp * 16 + 4*i + 0) * 136 + r] = (__bf16)vreg[i].x;
        vt[(qp * 16 + 4*i + 1) * 136 + r] = (__bf16)vreg[i].y;
        vt[(qp * 16 + 4*i + 2) * 136 + r] = (__bf16)vreg[i].z;
        vt[(qp * 16 + 4*i + 3) * 136 + r] = (__bf16)vreg[i].w;
    }
    __syncthreads();

    // ---- bo = P * V ----
    f32x4 accO[4];
#pragma unroll
    for (int nt = 0; nt < 4; nt++) accO[nt] = (f32x4){0.f, 0.f, 0.f, 0.f};
#pragma unroll
    for (int k0 = 0; k0 < 128; k0 += 32) {
        bf16x8 pa = *(const bf16x8*)(rs + (rbase + lo) * 136 + k0 + quad * 8);
#pragma unroll
        for (int nt = 0; nt < 4; nt++) {
            bf16x8 vb = *(const bf16x8*)(vt + (nt * 16 + lo) * 136 + k0 + quad * 8);
            accO[nt] = MFMA(pa, vb, accO[nt]);
        }
    }

    // ---- dense store (coalesced, no atomics) ----
    float* bb = bo + (size_t)bhc * (WW * DD);
#pragma unroll
    for (int rg = 0; rg < 4; rg++) {
        const int i = rbase + quad * 4 + rg;
#pragma unroll
        for (int nt = 0; nt < 4; nt++)
            bb[(size_t)i * DD + nt * 16 + lo] = accO[nt][rg];
    }
}

// ---------------------------------------------------------------------------
// Kernel 4: per-token gather-sum of dense bo rows + normalize (+ loss scalar)
// 16 lanes per token, 16 tokens per block.
// ---------------------------------------------------------------------------
__global__ __launch_bounds__(256) void k_out(
    const float* __restrict__ bo, const unsigned int* __restrict__ cnt,
    const unsigned short* __restrict__ inv, const double* __restrict__ lossa,
    float* __restrict__ out)
{
    const int tid = threadIdx.x;
    const int g = blockIdx.x * 16 + (tid >> 4);      // global token 0..262143
    const int l = tid & 15;
    const int bh = g >> 13;
    const unsigned int n = cnt[g];
    const int nc = (n < (unsigned)INVCAP) ? (int)n : INVCAP;
    const unsigned short* ip = inv + (size_t)g * INVCAP;
    const float* bbase = bo + (((size_t)bh << 13) * DD);
    float4 s = {0.f, 0.f, 0.f, 0.f};
    for (int e = 0; e < nc; e++) {
        const int slot = ip[e];
        float4 v4 = *(const float4*)(bbase + (size_t)slot * DD + l * 4);
        s.x += v4.x; s.y += v4.y; s.z += v4.z; s.w += v4.w;
    }
    const float r = 1.0f / ((float)n + 1e-5f);
    s.x *= r; s.y *= r; s.z *= r; s.w *= r;
    *(float4*)(out + (size_t)g * DD + l * 4) = s;
    if (g == 0 && l == 0) out[16777216] = (float)(lossa[0] * (0.0001 / 16777216.0));
}

// ---------------------------------------------------------------------------
extern "C" void kernel_launch(void* const* d_in, const int* in_sizes, int n_in,
                              void* d_out, int out_size, void* d_ws, size_t ws_size,
                              hipStream_t stream) {
    (void)in_sizes; (void)n_in; (void)ws_size; (void)out_size;
    const float* qk    = (const float*)d_in[0];
    const float* v     = (const float*)d_in[1];
    const float* means = (const float*)d_in[2];
    const float* rel_w = (const float*)d_in[3];
    float* out = (float*)d_out;

    // ws layout:
    //   [keys u64 134MB]          (bo 67MB aliases front half after k_topk)
    //   [idx 1MB]                 (means64 256KB aliases: read before idx written)
    //   [cnt 1MB][lossa 4KB pad]  (memset region)
    //   [inv u16 cap24 12.6MB]
    char* ws = (char*)d_ws;
    const size_t KEYS_B = (size_t)BHN * NC * TT * 8;        // 134217728
    const size_t IDX_B  = (size_t)BHN * NC * WW * 4;        // 1048576
    const size_t CNT_B  = (size_t)BHN * TT * 4;             // 1048576
    u64*            keys    = (u64*)ws;
    float*          bo      = (float*)ws;                    // alias, post-k_topk
    int*            idx     = (int*)(ws + KEYS_B);
    double*         means64 = (double*)(ws + KEYS_B);        // alias, pre-k_topk
    unsigned int*   cnt     = (unsigned int*)(ws + KEYS_B + IDX_B);
    double*         lossa   = (double*)(ws + KEYS_B + IDX_B + CNT_B);
    unsigned short* inv     = (unsigned short*)(ws + KEYS_B + IDX_B + CNT_B + 4096);

    hipMemsetAsync(ws + KEYS_B + IDX_B, 0, CNT_B + 4096, stream);

    k_prep<<<NH * NC * DD / 256, 256, 0, stream>>>(means, means64);
    k_dists<<<dim3(BHN, TT / 256), 256, 0, stream>>>(qk, means64, keys, lossa);
    k_topk<<<BHN * NC, 256, 0, stream>>>(keys, idx, cnt, inv);
    k_attn<<<BHN * NC, 512, 0, stream>>>(qk, v, rel_w, idx, bo);
    k_out<<<BHN * TT / 16, 256, 0, stream>>>(bo, cnt, inv, lossa, out);
}